// Round 12
// baseline (466.735 us; speedup 1.0000x reference)
//
#include <hip/hip_runtime.h>

#define Bb 8
#define Nn 2048
#define Dd 512

#define KV 32            // keys per tile/image
#define NT 64            // images per batch
#define NTT 32           // tiles per stream (1024 keys)
#define PP2 40           // sP row stride (elements)

// fallback (no ws): R10 structure
#define KVF 64
#define NTF (Nn / KVF)
#define PPF 72

typedef __attribute__((ext_vector_type(8))) short bf8;
typedef __attribute__((ext_vector_type(4))) float f4;
struct __align__(16) U8 { unsigned short s[8]; };

__device__ __forceinline__ unsigned short f2bf(float f) {
  union { float f; unsigned u; } v; v.f = f;
  unsigned r = v.u + 0x7fffu + ((v.u >> 16) & 1u);
  return (unsigned short)(r >> 16);
}

// ---------------------------------------------------------------------------
// Build per-(b,tile) LDS images in ws, once.  Image = [sK 16384 | sVt 16384] u16.
//   sK : key*512 + ((c ^ (key&7))<<3), c = d>>3
//   sVt: 16384 + d*32 + ((g ^ ((d>>1)&3))<<3), g = key>>3
// ---------------------------------------------------------------------------
__global__ __launch_bounds__(256)
void build_images(const float* __restrict__ X, unsigned short* __restrict__ W) {
  __shared__ float sT[KV * Dd];  // 64 KB
  const int t = blockIdx.x, b = blockIdx.y, tid = threadIdx.x;
  const float* src = X + ((size_t)b * Nn + t * KV) * Dd;
#pragma unroll
  for (int i = 0; i < 16; ++i) {
    int idx = i * 256 + tid;
    *(float4*)(sT + idx * 4) = *(const float4*)(src + idx * 4);
  }
  __syncthreads();
  unsigned short* img = W + ((size_t)(b * NT + t) << 15);
#pragma unroll
  for (int i = 0; i < 8; ++i) {
    int idx = i * 256 + tid;
    int key = idx >> 6, c = idx & 63;
    const float* p = sT + key * Dd + c * 8;
    U8 v;
#pragma unroll
    for (int j = 0; j < 8; ++j) v.s[j] = f2bf(p[j]);
    *(U8*)(img + key * 512 + ((c ^ (key & 7)) << 3)) = v;
  }
#pragma unroll
  for (int i = 0; i < 8; ++i) {
    int idx = i * 256 + tid;
    int d = idx >> 2, g = idx & 3;
    U8 v;
#pragma unroll
    for (int e = 0; e < 8; ++e) v.s[e] = f2bf(sT[(g * 8 + e) * Dd + d]);
    *(U8*)(img + 16384 + d * 32 + ((g ^ ((d >> 1) & 3)) << 3)) = v;
  }
}

// ---------------------------------------------------------------------------
// K-split attention: 512 thr = 8 waves. Waves 0-3: keys 0-1023, waves 4-7:
// keys 1024-2047, same 64 q-rows. Flash-merge of the two halves in LDS.
// 2 waves/SIMD (vs 1 before) -> latency overlap; 32 serial tiles per wave.
// ---------------------------------------------------------------------------
__global__ __launch_bounds__(512, 2)
void attn_ksplit(const unsigned short* __restrict__ W, const int* __restrict__ mask,
                 float* __restrict__ out) {
  __shared__ unsigned short sImg[2][32768];   // per-stream tile image, 128 KB
  __shared__ unsigned short sP[8][16 * PP2];  // 10 KB
  __shared__ float sML[8][32];                // m/l exchange, 1 KB

  const int tid  = threadIdx.x;
  const int wave = tid >> 6, lane = tid & 63;
  const int lg = lane >> 4, ll = lane & 15;
  const int half = wave >> 2, w4 = wave & 3;
  const int stid = tid & 255;                 // staging id within stream
  const int bid = blockIdx.x;
  const int b  = bid & 7;                     // XCD-batch affinity
  const int q0 = (bid >> 3) * 64 + w4 * 16;
  const int bN = b * NT;
  const float scale = 0.044194173824159216f;  // 1/sqrt(512)

  unsigned short* myimg = sImg[half];

  // Q fragments from the images (same layout math as K reads)
  bf8 qf[16];
  {
    int qrow = q0 + ll;
    const unsigned short* qimg = W + ((size_t)(bN + (qrow >> 5)) << 15);
    int key = qrow & 31;
#pragma unroll
    for (int ch = 0; ch < 16; ++ch) {
      int c = ch * 4 + lg;
      qf[ch] = *(const bf8*)(qimg + key * 512 + ((c ^ (key & 7)) << 3));
    }
  }

  float bias[4];
#pragma unroll
  for (int r = 0; r < 4; ++r)
    bias[r] = (1.0f - (float)mask[b * Nn + q0 + lg * 4 + r]) * 1e9f;

  float m[4], lsum[4];
  f4 o[32];
#pragma unroll
  for (int r = 0; r < 4; ++r) { m[r] = -1e30f; lsum[r] = 0.0f; }
#pragma unroll
  for (int ct = 0; ct < 32; ++ct) o[ct] = (f4){0.f, 0.f, 0.f, 0.f};

  // prologue: stage first tile of this stream
  {
    const unsigned short* img0 = W + ((size_t)(bN + half * NTT) << 15);
#pragma unroll
    for (int i = 0; i < 16; ++i) {
      U8 v = *(const U8*)(img0 + (i * 256 + stid) * 8);
      *(U8*)(myimg + (i * 256 + stid) * 8) = v;
    }
  }
  __syncthreads();

  for (int tt = 0; tt < NTT; ++tt) {
    const bool pf = (tt + 1 < NTT);
    const unsigned short* imgn = W + ((size_t)(bN + half * NTT + tt + 1) << 15);

    // prefetch K-image half of next tile (hides under QK^T)
    U8 stA[8];
    if (pf) {
#pragma unroll
      for (int i = 0; i < 8; ++i) stA[i] = *(const U8*)(imgn + (i * 256 + stid) * 8);
    }

    // ---- QK^T: S[16 x 32] ----
    f4 s2[2];
    s2[0] = (f4){0.f, 0.f, 0.f, 0.f};
    s2[1] = (f4){0.f, 0.f, 0.f, 0.f};
#pragma unroll
    for (int ch = 0; ch < 16; ++ch) {
#pragma unroll
      for (int cc = 0; cc < 2; ++cc) {
        int key = cc * 16 + ll;
        bf8 kf = *(const bf8*)(myimg + key * 512 + (((ch * 4 + lg) ^ (key & 7)) << 3));
        s2[cc] = __builtin_amdgcn_mfma_f32_16x16x32_bf16(qf[ch], kf, s2[cc], 0, 0, 0);
      }
    }
    __syncthreads();  // bar1: all waves done reading sK region

    // write next K-image (ds_writes interleave with softmax below)
    if (pf) {
#pragma unroll
      for (int i = 0; i < 8; ++i) *(U8*)(myimg + (i * 256 + stid) * 8) = stA[i];
    }
    // prefetch V-image half (hides under softmax + PV)
    U8 stB[8];
    if (pf) {
#pragma unroll
      for (int i = 0; i < 8; ++i) stB[i] = *(const U8*)(imgn + ((i + 8) * 256 + stid) * 8);
    }

    // ---- online softmax ----
    float e2[2][4];
#pragma unroll
    for (int cc = 0; cc < 2; ++cc)
#pragma unroll
      for (int r = 0; r < 4; ++r)
        e2[cc][r] = s2[cc][r] * scale - bias[r];  // f32: masked rows -> exactly -1e9

    float tm[4];
#pragma unroll
    for (int r = 0; r < 4; ++r) tm[r] = fmaxf(e2[0][r], e2[1][r]);
#pragma unroll
    for (int off = 1; off < 16; off <<= 1)
#pragma unroll
      for (int r = 0; r < 4; ++r) tm[r] = fmaxf(tm[r], __shfl_xor(tm[r], off));

    float mn[4];
    bool change = false;
#pragma unroll
    for (int r = 0; r < 4; ++r) { mn[r] = fmaxf(m[r], tm[r]); change = change || (mn[r] > m[r]); }
    if (__any(change)) {
#pragma unroll
      for (int r = 0; r < 4; ++r) {
        float al = __expf(m[r] - mn[r]);
        lsum[r] *= al;
        m[r] = mn[r];
#pragma unroll
        for (int ct = 0; ct < 32; ++ct) o[ct][r] *= al;
      }
    }

    float ts[4] = {0.f, 0.f, 0.f, 0.f};
    unsigned short pb[2][4];
#pragma unroll
    for (int cc = 0; cc < 2; ++cc)
#pragma unroll
      for (int r = 0; r < 4; ++r) {
        float p = __expf(e2[cc][r] - m[r]);
        ts[r] += p;
        pb[cc][r] = f2bf(p);
      }
#pragma unroll
    for (int off = 1; off < 16; off <<= 1)
#pragma unroll
      for (int r = 0; r < 4; ++r) ts[r] += __shfl_xor(ts[r], off);
#pragma unroll
    for (int r = 0; r < 4; ++r) lsum[r] += ts[r];

    // ---- P round-trip (C-layout write, A-layout read; same wave) ----
    unsigned short* Pw = sP[wave];
#pragma unroll
    for (int cc = 0; cc < 2; ++cc)
#pragma unroll
      for (int r = 0; r < 4; ++r)
        Pw[(lg * 4 + r) * PP2 + cc * 16 + ll] = pb[cc][r];
    bf8 af = *(const bf8*)(Pw + ll * PP2 + lg * 8);

    // ---- PV: O[16 x 512] += P[16 x 32] * V[32 x 512] ----
    const unsigned short* sV = myimg + 16384;
#pragma unroll
    for (int ct = 0; ct < 32; ++ct) {
      int d = ct * 16 + ll;
      bf8 vf = *(const bf8*)(sV + d * 32 + ((lg ^ ((d >> 1) & 3)) << 3));
      o[ct] = __builtin_amdgcn_mfma_f32_16x16x32_bf16(af, vf, o[ct], 0, 0, 0);
    }
    __syncthreads();  // bar2: all waves done reading sVt region

    if (pf) {
#pragma unroll
      for (int i = 0; i < 8; ++i) *(U8*)(myimg + ((i + 8) * 256 + stid) * 8) = stB[i];
    }
    __syncthreads();  // bar3: next tile's images visible
  }

  // ---- flash-merge of the two key-halves ----
  if (ll == 0) {
#pragma unroll
    for (int r = 0; r < 4; ++r) {
      int row = lg * 4 + r;
      sML[wave][row] = m[r];
      sML[wave][16 + row] = lsum[r];
    }
  }
  __syncthreads();

  float as[4], L[4];
#pragma unroll
  for (int r = 0; r < 4; ++r) {
    int row = lg * 4 + r;
    float mo = sML[wave ^ 4][row];
    float lo = sML[wave ^ 4][16 + row];
    float M = fmaxf(m[r], mo);
    as[r] = __expf(m[r] - M);
    float ao = __expf(mo - M);
    L[r] = lsum[r] * as[r] + lo * ao;
  }

  float* fbuf = (float*)(&sImg[0][0]) + w4 * 8192;  // 32 KB chunk per pair
  if (half == 1) {
#pragma unroll
    for (int ct = 0; ct < 32; ++ct)
#pragma unroll
      for (int r = 0; r < 4; ++r)
        fbuf[(lg * 4 + r) * 512 + ct * 16 + ll] = as[r] * o[ct][r];
  }
  __syncthreads();
  if (half == 0) {
    float inv[4];
#pragma unroll
    for (int r = 0; r < 4; ++r) inv[r] = 1.0f / L[r];
#pragma unroll
    for (int ct = 0; ct < 32; ++ct)
#pragma unroll
      for (int r = 0; r < 4; ++r) {
        size_t row = (size_t)b * Nn + q0 + lg * 4 + r;
        out[row * Dd + ct * 16 + ll] =
            (as[r] * o[ct][r] + fbuf[(lg * 4 + r) * 512 + ct * 16 + ll]) * inv[r];
      }
  }
}

// ---------------------------------------------------------------------------
// Fallback (ws too small): R10 structure, KV=64, in-kernel convert.
// ---------------------------------------------------------------------------
__global__ __launch_bounds__(256, 1)
void attn_fb(const float* __restrict__ Xf, const int* __restrict__ mask,
             float* __restrict__ out) {
  __shared__ unsigned short sK[KVF * Dd];
  __shared__ unsigned short sVt[Dd * KVF];
  __shared__ unsigned short sPf[4][16 * PPF];

  const int tid  = threadIdx.x;
  const int wave = tid >> 6, lane = tid & 63;
  const int lg = lane >> 4, ll = lane & 15;
  const int b  = blockIdx.y;
  const int q0 = blockIdx.x * 64 + wave * 16;

  bf8 qf[16];
  {
    const size_t qoff = ((size_t)b * Nn + q0 + ll) * Dd;
#pragma unroll
    for (int ch = 0; ch < 16; ++ch) {
      int doff = ch * 32 + lg * 8;
      float4 a = *(const float4*)(Xf + qoff + doff);
      float4 c = *(const float4*)(Xf + qoff + doff + 4);
      bf8 tt;
      tt[0] = (short)f2bf(a.x); tt[1] = (short)f2bf(a.y);
      tt[2] = (short)f2bf(a.z); tt[3] = (short)f2bf(a.w);
      tt[4] = (short)f2bf(c.x); tt[5] = (short)f2bf(c.y);
      tt[6] = (short)f2bf(c.z); tt[7] = (short)f2bf(c.w);
      qf[ch] = tt;
    }
  }
  float bias[4];
#pragma unroll
  for (int r = 0; r < 4; ++r)
    bias[r] = (1.0f - (float)mask[b * Nn + q0 + lg * 4 + r]) * 1e9f;
  float m[4], lsum[4];
  f4 o[32];
#pragma unroll
  for (int r = 0; r < 4; ++r) { m[r] = -1e30f; lsum[r] = 0.0f; }
#pragma unroll
  for (int ct = 0; ct < 32; ++ct) o[ct] = (f4){0.f, 0.f, 0.f, 0.f};
  const float scale = 0.044194173824159216f;

  for (int t = 0; t < NTF; ++t) {
    __syncthreads();
    const size_t base = ((size_t)b * Nn + t * KVF) * Dd;
#pragma unroll
    for (int it = 0; it < 16; ++it) {
      int idx = it * 256 + tid;
      int key = idx >> 6, c = idx & 63;
      const float* sp = Xf + base + key * Dd + c * 8;
      float4 a = *(const float4*)(sp);
      float4 d2 = *(const float4*)(sp + 4);
      U8 v;
      v.s[0] = f2bf(a.x); v.s[1] = f2bf(a.y); v.s[2] = f2bf(a.z); v.s[3] = f2bf(a.w);
      v.s[4] = f2bf(d2.x); v.s[5] = f2bf(d2.y); v.s[6] = f2bf(d2.z); v.s[7] = f2bf(d2.w);
      *(U8*)(sK + key * 512 + ((c ^ (key & 7)) << 3)) = v;
      int ko = key >> 3, k7 = key & 7;
#pragma unroll
      for (int j = 0; j < 8; ++j) {
        int dd = c * 8 + j;
        sVt[dd * 64 + ((ko ^ j ^ (c & 7)) << 3) + k7] = v.s[j];
      }
    }
    __syncthreads();

    f4 s[4];
#pragma unroll
    for (int cc = 0; cc < 4; ++cc) s[cc] = (f4){0.f, 0.f, 0.f, 0.f};
#pragma unroll
    for (int ch = 0; ch < 16; ++ch)
#pragma unroll
      for (int cc = 0; cc < 4; ++cc) {
        int key = cc * 16 + ll;
        bf8 kf = *(const bf8*)(sK + key * 512 + (((ch * 4 + lg) ^ (key & 7)) << 3));
        s[cc] = __builtin_amdgcn_mfma_f32_16x16x32_bf16(qf[ch], kf, s[cc], 0, 0, 0);
      }

    float e[4][4];
#pragma unroll
    for (int cc = 0; cc < 4; ++cc)
#pragma unroll
      for (int r = 0; r < 4; ++r) e[cc][r] = s[cc][r] * scale - bias[r];
    float tm[4];
#pragma unroll
    for (int r = 0; r < 4; ++r)
      tm[r] = fmaxf(fmaxf(e[0][r], e[1][r]), fmaxf(e[2][r], e[3][r]));
#pragma unroll
    for (int off = 1; off < 16; off <<= 1)
#pragma unroll
      for (int r = 0; r < 4; ++r) tm[r] = fmaxf(tm[r], __shfl_xor(tm[r], off));
    float mn[4]; bool change = false;
#pragma unroll
    for (int r = 0; r < 4; ++r) { mn[r] = fmaxf(m[r], tm[r]); change = change || (mn[r] > m[r]); }
    if (__any(change)) {
#pragma unroll
      for (int r = 0; r < 4; ++r) {
        float al = __expf(m[r] - mn[r]);
        lsum[r] *= al; m[r] = mn[r];
#pragma unroll
        for (int ct = 0; ct < 32; ++ct) o[ct][r] *= al;
      }
    }
    float ts[4] = {0.f, 0.f, 0.f, 0.f};
    unsigned short pb[4][4];
#pragma unroll
    for (int cc = 0; cc < 4; ++cc)
#pragma unroll
      for (int r = 0; r < 4; ++r) {
        float p = __expf(e[cc][r] - m[r]);
        ts[r] += p; pb[cc][r] = f2bf(p);
      }
#pragma unroll
    for (int off = 1; off < 16; off <<= 1)
#pragma unroll
      for (int r = 0; r < 4; ++r) ts[r] += __shfl_xor(ts[r], off);
#pragma unroll
    for (int r = 0; r < 4; ++r) lsum[r] += ts[r];

    unsigned short* Pw = sPf[wave];
#pragma unroll
    for (int cc = 0; cc < 4; ++cc)
#pragma unroll
      for (int r = 0; r < 4; ++r)
        Pw[(lg * 4 + r) * PPF + cc * 16 + ll] = pb[cc][r];
#pragma unroll
    for (int kc = 0; kc < 2; ++kc) {
      bf8 af = *(const bf8*)(Pw + ll * PPF + kc * 32 + lg * 8);
#pragma unroll
      for (int ct = 0; ct < 32; ++ct) {
        int d = ct * 16 + ll;
        bf8 vf = *(const bf8*)(sVt + d * 64 + (((kc * 4 + lg) ^ (d & 7) ^ ((d >> 3) & 7)) << 3));
        o[ct] = __builtin_amdgcn_mfma_f32_16x16x32_bf16(af, vf, o[ct], 0, 0, 0);
      }
    }
  }
  float inv[4];
#pragma unroll
  for (int r = 0; r < 4; ++r) inv[r] = 1.0f / lsum[r];
#pragma unroll
  for (int ct = 0; ct < 32; ++ct)
#pragma unroll
    for (int r = 0; r < 4; ++r) {
      size_t row = (size_t)b * Nn + q0 + lg * 4 + r;
      out[row * Dd + ct * 16 + ll] = o[ct][r] * inv[r];
    }
}

extern "C" void kernel_launch(void* const* d_in, const int* in_sizes, int n_in,
                              void* d_out, int out_size, void* d_ws, size_t ws_size,
                              hipStream_t stream) {
  (void)in_sizes; (void)n_in; (void)out_size;
  const float* X  = (const float*)d_in[0];
  const int* mask = (const int*)d_in[1];
  float* out = (float*)d_out;

  const size_t need = (size_t)Bb * NT * 65536;  // 32 MB of bf16 images
  if (ws_size >= need) {
    unsigned short* W = (unsigned short*)d_ws;
    build_images<<<dim3(NT, Bb), 256, 0, stream>>>(X, W);
    attn_ksplit<<<256, 512, 0, stream>>>(W, mask, out);
  } else {
    attn_fb<<<dim3(Nn / 64, Bb), 256, 0, stream>>>(X, mask, out);
  }
}

// Round 13
// 461.355 us; speedup vs baseline: 1.0117x; 1.0117x over previous
//
#include <hip/hip_runtime.h>

#define Bb 8
#define Nn 2048
#define Dd 512

#define KV 32            // keys per tile/image
#define NT 64            // images per batch
#define NTT 32           // tiles per stream (1024 keys)
#define PP2 40           // sP row stride (elements)

// fallback (no ws): R10 structure
#define KVF 64
#define NTF (Nn / KVF)
#define PPF 72

typedef __attribute__((ext_vector_type(8))) short bf8;
typedef __attribute__((ext_vector_type(4))) float f4;
struct __align__(16) U8 { unsigned short s[8]; };

__device__ __forceinline__ unsigned short f2bf(float f) {
  union { float f; unsigned u; } v; v.f = f;
  unsigned r = v.u + 0x7fffu + ((v.u >> 16) & 1u);
  return (unsigned short)(r >> 16);
}

// ---------------------------------------------------------------------------
// Build per-(b,tile) LDS images in ws, once.  Image = [sK 16384 | sVt 16384] u16.
//   sK : key*512 + ((c ^ (key&7))<<3), c = d>>3
//   sVt: 16384 + d*32 + ((g ^ ((d>>1)&3))<<3), g = key>>3
// ---------------------------------------------------------------------------
__global__ __launch_bounds__(256)
void build_images(const float* __restrict__ X, unsigned short* __restrict__ W) {
  __shared__ float sT[KV * Dd];  // 64 KB
  const int t = blockIdx.x, b = blockIdx.y, tid = threadIdx.x;
  const float* src = X + ((size_t)b * Nn + t * KV) * Dd;
#pragma unroll
  for (int i = 0; i < 16; ++i) {
    int idx = i * 256 + tid;
    *(float4*)(sT + idx * 4) = *(const float4*)(src + idx * 4);
  }
  __syncthreads();
  unsigned short* img = W + ((size_t)(b * NT + t) << 15);
#pragma unroll
  for (int i = 0; i < 8; ++i) {
    int idx = i * 256 + tid;
    int key = idx >> 6, c = idx & 63;
    const float* p = sT + key * Dd + c * 8;
    U8 v;
#pragma unroll
    for (int j = 0; j < 8; ++j) v.s[j] = f2bf(p[j]);
    *(U8*)(img + key * 512 + ((c ^ (key & 7)) << 3)) = v;
  }
#pragma unroll
  for (int i = 0; i < 8; ++i) {
    int idx = i * 256 + tid;
    int d = idx >> 2, g = idx & 3;
    U8 v;
#pragma unroll
    for (int e = 0; e < 8; ++e) v.s[e] = f2bf(sT[(g * 8 + e) * Dd + d]);
    *(U8*)(img + 16384 + d * 32 + ((g ^ ((d >> 1) & 3)) << 3)) = v;
  }
}

// ---------------------------------------------------------------------------
// K-split attention: 512 thr = 8 waves. Waves 0-3: keys 0-1023, waves 4-7:
// keys 1024-2047, same 64 q-rows; in-block flash-merge at the end.
// launch_bounds(512,1): 2nd arg is min-BLOCKS-per-CU on this compiler —
// (512,2) capped VGPRs at 128 and spilled ~1.5 GB to scratch (R12).
// 2 barriers per tile (bar3 removed: V-writes ordered by next tile's bar1).
// ---------------------------------------------------------------------------
__global__ __launch_bounds__(512, 1)
void attn_ksplit(const unsigned short* __restrict__ W, const int* __restrict__ mask,
                 float* __restrict__ out) {
  __shared__ unsigned short sImg[2][32768];   // per-stream tile image, 128 KB
  __shared__ unsigned short sP[8][16 * PP2];  // 10 KB
  __shared__ float sML[8][32];                // m/l exchange, 1 KB

  const int tid  = threadIdx.x;
  const int wave = tid >> 6, lane = tid & 63;
  const int lg = lane >> 4, ll = lane & 15;
  const int half = wave >> 2, w4 = wave & 3;
  const int stid = tid & 255;                 // staging id within stream
  const int bid = blockIdx.x;
  const int b  = bid & 7;                     // XCD-batch affinity
  const int q0 = (bid >> 3) * 64 + w4 * 16;
  const int bN = b * NT;
  const float scale = 0.044194173824159216f;  // 1/sqrt(512)

  unsigned short* myimg = sImg[half];

  // Q fragments from the images (same layout math as K reads)
  bf8 qf[16];
  {
    int qrow = q0 + ll;
    const unsigned short* qimg = W + ((size_t)(bN + (qrow >> 5)) << 15);
    int key = qrow & 31;
#pragma unroll
    for (int ch = 0; ch < 16; ++ch) {
      int c = ch * 4 + lg;
      qf[ch] = *(const bf8*)(qimg + key * 512 + ((c ^ (key & 7)) << 3));
    }
  }

  float bias[4];
#pragma unroll
  for (int r = 0; r < 4; ++r)
    bias[r] = (1.0f - (float)mask[b * Nn + q0 + lg * 4 + r]) * 1e9f;

  float m[4], lsum[4];
  f4 o[32];
#pragma unroll
  for (int r = 0; r < 4; ++r) { m[r] = -1e30f; lsum[r] = 0.0f; }
#pragma unroll
  for (int ct = 0; ct < 32; ++ct) o[ct] = (f4){0.f, 0.f, 0.f, 0.f};

  // prologue: stage first tile of this stream
  {
    const unsigned short* img0 = W + ((size_t)(bN + half * NTT) << 15);
#pragma unroll
    for (int i = 0; i < 16; ++i) {
      U8 v = *(const U8*)(img0 + (i * 256 + stid) * 8);
      *(U8*)(myimg + (i * 256 + stid) * 8) = v;
    }
  }
  __syncthreads();

  for (int tt = 0; tt < NTT; ++tt) {
    const bool pf = (tt + 1 < NTT);
    const unsigned short* imgn = W + ((size_t)(bN + half * NTT + tt + 1) << 15);

    // prefetch K-image half of next tile (hides under QK^T)
    U8 stA[8];
    if (pf) {
#pragma unroll
      for (int i = 0; i < 8; ++i) stA[i] = *(const U8*)(imgn + (i * 256 + stid) * 8);
    }

    // ---- QK^T: S[16 x 32] ----
    f4 s2[2];
    s2[0] = (f4){0.f, 0.f, 0.f, 0.f};
    s2[1] = (f4){0.f, 0.f, 0.f, 0.f};
#pragma unroll
    for (int ch = 0; ch < 16; ++ch) {
#pragma unroll
      for (int cc = 0; cc < 2; ++cc) {
        int key = cc * 16 + ll;
        bf8 kf = *(const bf8*)(myimg + key * 512 + (((ch * 4 + lg) ^ (key & 7)) << 3));
        s2[cc] = __builtin_amdgcn_mfma_f32_16x16x32_bf16(qf[ch], kf, s2[cc], 0, 0, 0);
      }
    }
    __syncthreads();  // bar1: all waves done reading K-region

    // write next K-image (ds_writes hide under softmax below)
    if (pf) {
#pragma unroll
      for (int i = 0; i < 8; ++i) *(U8*)(myimg + (i * 256 + stid) * 8) = stA[i];
    }
    // prefetch V-image half (hides under softmax + PV)
    U8 stB[8];
    if (pf) {
#pragma unroll
      for (int i = 0; i < 8; ++i) stB[i] = *(const U8*)(imgn + ((i + 8) * 256 + stid) * 8);
    }

    // ---- online softmax ----
    float e2[2][4];
#pragma unroll
    for (int cc = 0; cc < 2; ++cc)
#pragma unroll
      for (int r = 0; r < 4; ++r)
        e2[cc][r] = s2[cc][r] * scale - bias[r];  // f32: masked rows -> exactly -1e9

    float tm[4];
#pragma unroll
    for (int r = 0; r < 4; ++r) tm[r] = fmaxf(e2[0][r], e2[1][r]);
#pragma unroll
    for (int off = 1; off < 16; off <<= 1)
#pragma unroll
      for (int r = 0; r < 4; ++r) tm[r] = fmaxf(tm[r], __shfl_xor(tm[r], off));

    float mn[4];
    bool change = false;
#pragma unroll
    for (int r = 0; r < 4; ++r) { mn[r] = fmaxf(m[r], tm[r]); change = change || (mn[r] > m[r]); }
    if (__any(change)) {
#pragma unroll
      for (int r = 0; r < 4; ++r) {
        float al = __expf(m[r] - mn[r]);
        lsum[r] *= al;
        m[r] = mn[r];
#pragma unroll
        for (int ct = 0; ct < 32; ++ct) o[ct][r] *= al;
      }
    }

    float ts[4] = {0.f, 0.f, 0.f, 0.f};
    unsigned short pb[2][4];
#pragma unroll
    for (int cc = 0; cc < 2; ++cc)
#pragma unroll
      for (int r = 0; r < 4; ++r) {
        float p = __expf(e2[cc][r] - m[r]);
        ts[r] += p;
        pb[cc][r] = f2bf(p);
      }
#pragma unroll
    for (int off = 1; off < 16; off <<= 1)
#pragma unroll
      for (int r = 0; r < 4; ++r) ts[r] += __shfl_xor(ts[r], off);
#pragma unroll
    for (int r = 0; r < 4; ++r) lsum[r] += ts[r];

    // ---- P round-trip (C-layout write, A-layout read; same wave) ----
    unsigned short* Pw = sP[wave];
#pragma unroll
    for (int cc = 0; cc < 2; ++cc)
#pragma unroll
      for (int r = 0; r < 4; ++r)
        Pw[(lg * 4 + r) * PP2 + cc * 16 + ll] = pb[cc][r];
    bf8 af = *(const bf8*)(Pw + ll * PP2 + lg * 8);

    // ---- PV: O[16 x 512] += P[16 x 32] * V[32 x 512] ----
    const unsigned short* sV = myimg + 16384;
#pragma unroll
    for (int ct = 0; ct < 32; ++ct) {
      int d = ct * 16 + ll;
      bf8 vf = *(const bf8*)(sV + d * 32 + ((lg ^ ((d >> 1) & 3)) << 3));
      o[ct] = __builtin_amdgcn_mfma_f32_16x16x32_bf16(af, vf, o[ct], 0, 0, 0);
    }
    __syncthreads();  // bar2: all waves done reading V-region

    // write next V-image; ordered against next PV by next iteration's bar1
    if (pf) {
#pragma unroll
      for (int i = 0; i < 8; ++i) *(U8*)(myimg + ((i + 8) * 256 + stid) * 8) = stB[i];
    }
  }

  // ---- flash-merge of the two key-halves ----
  if (ll == 0) {
#pragma unroll
    for (int r = 0; r < 4; ++r) {
      int row = lg * 4 + r;
      sML[wave][row] = m[r];
      sML[wave][16 + row] = lsum[r];
    }
  }
  __syncthreads();

  float as[4], L[4];
#pragma unroll
  for (int r = 0; r < 4; ++r) {
    int row = lg * 4 + r;
    float mo = sML[wave ^ 4][row];
    float lo = sML[wave ^ 4][16 + row];
    float M = fmaxf(m[r], mo);
    as[r] = __expf(m[r] - M);
    float ao = __expf(mo - M);
    L[r] = lsum[r] * as[r] + lo * ao;
  }

  float* fbuf = (float*)(&sImg[0][0]) + w4 * 8192;  // 32 KB chunk per pair
  if (half == 1) {
#pragma unroll
    for (int ct = 0; ct < 32; ++ct)
#pragma unroll
      for (int r = 0; r < 4; ++r)
        fbuf[(lg * 4 + r) * 512 + ct * 16 + ll] = as[r] * o[ct][r];
  }
  __syncthreads();
  if (half == 0) {
    float inv[4];
#pragma unroll
    for (int r = 0; r < 4; ++r) inv[r] = 1.0f / L[r];
#pragma unroll
    for (int ct = 0; ct < 32; ++ct)
#pragma unroll
      for (int r = 0; r < 4; ++r) {
        size_t row = (size_t)b * Nn + q0 + lg * 4 + r;
        out[row * Dd + ct * 16 + ll] =
            (as[r] * o[ct][r] + fbuf[(lg * 4 + r) * 512 + ct * 16 + ll]) * inv[r];
      }
  }
}

// ---------------------------------------------------------------------------
// Fallback (ws too small): R10 structure, KV=64, in-kernel convert.
// ---------------------------------------------------------------------------
__global__ __launch_bounds__(256, 1)
void attn_fb(const float* __restrict__ Xf, const int* __restrict__ mask,
             float* __restrict__ out) {
  __shared__ unsigned short sK[KVF * Dd];
  __shared__ unsigned short sVt[Dd * KVF];
  __shared__ unsigned short sPf[4][16 * PPF];

  const int tid  = threadIdx.x;
  const int wave = tid >> 6, lane = tid & 63;
  const int lg = lane >> 4, ll = lane & 15;
  const int b  = blockIdx.y;
  const int q0 = blockIdx.x * 64 + wave * 16;

  bf8 qf[16];
  {
    const size_t qoff = ((size_t)b * Nn + q0 + ll) * Dd;
#pragma unroll
    for (int ch = 0; ch < 16; ++ch) {
      int doff = ch * 32 + lg * 8;
      float4 a = *(const float4*)(Xf + qoff + doff);
      float4 c = *(const float4*)(Xf + qoff + doff + 4);
      bf8 tt;
      tt[0] = (short)f2bf(a.x); tt[1] = (short)f2bf(a.y);
      tt[2] = (short)f2bf(a.z); tt[3] = (short)f2bf(a.w);
      tt[4] = (short)f2bf(c.x); tt[5] = (short)f2bf(c.y);
      tt[6] = (short)f2bf(c.z); tt[7] = (short)f2bf(c.w);
      qf[ch] = tt;
    }
  }
  float bias[4];
#pragma unroll
  for (int r = 0; r < 4; ++r)
    bias[r] = (1.0f - (float)mask[b * Nn + q0 + lg * 4 + r]) * 1e9f;
  float m[4], lsum[4];
  f4 o[32];
#pragma unroll
  for (int r = 0; r < 4; ++r) { m[r] = -1e30f; lsum[r] = 0.0f; }
#pragma unroll
  for (int ct = 0; ct < 32; ++ct) o[ct] = (f4){0.f, 0.f, 0.f, 0.f};
  const float scale = 0.044194173824159216f;

  for (int t = 0; t < NTF; ++t) {
    __syncthreads();
    const size_t base = ((size_t)b * Nn + t * KVF) * Dd;
#pragma unroll
    for (int it = 0; it < 16; ++it) {
      int idx = it * 256 + tid;
      int key = idx >> 6, c = idx & 63;
      const float* sp = Xf + base + key * Dd + c * 8;
      float4 a = *(const float4*)(sp);
      float4 d2 = *(const float4*)(sp + 4);
      U8 v;
      v.s[0] = f2bf(a.x); v.s[1] = f2bf(a.y); v.s[2] = f2bf(a.z); v.s[3] = f2bf(a.w);
      v.s[4] = f2bf(d2.x); v.s[5] = f2bf(d2.y); v.s[6] = f2bf(d2.z); v.s[7] = f2bf(d2.w);
      *(U8*)(sK + key * 512 + ((c ^ (key & 7)) << 3)) = v;
      int ko = key >> 3, k7 = key & 7;
#pragma unroll
      for (int j = 0; j < 8; ++j) {
        int dd = c * 8 + j;
        sVt[dd * 64 + ((ko ^ j ^ (c & 7)) << 3) + k7] = v.s[j];
      }
    }
    __syncthreads();

    f4 s[4];
#pragma unroll
    for (int cc = 0; cc < 4; ++cc) s[cc] = (f4){0.f, 0.f, 0.f, 0.f};
#pragma unroll
    for (int ch = 0; ch < 16; ++ch)
#pragma unroll
      for (int cc = 0; cc < 4; ++cc) {
        int key = cc * 16 + ll;
        bf8 kf = *(const bf8*)(sK + key * 512 + (((ch * 4 + lg) ^ (key & 7)) << 3));
        s[cc] = __builtin_amdgcn_mfma_f32_16x16x32_bf16(qf[ch], kf, s[cc], 0, 0, 0);
      }

    float e[4][4];
#pragma unroll
    for (int cc = 0; cc < 4; ++cc)
#pragma unroll
      for (int r = 0; r < 4; ++r) e[cc][r] = s[cc][r] * scale - bias[r];
    float tm[4];
#pragma unroll
    for (int r = 0; r < 4; ++r)
      tm[r] = fmaxf(fmaxf(e[0][r], e[1][r]), fmaxf(e[2][r], e[3][r]));
#pragma unroll
    for (int off = 1; off < 16; off <<= 1)
#pragma unroll
      for (int r = 0; r < 4; ++r) tm[r] = fmaxf(tm[r], __shfl_xor(tm[r], off));
    float mn[4]; bool change = false;
#pragma unroll
    for (int r = 0; r < 4; ++r) { mn[r] = fmaxf(m[r], tm[r]); change = change || (mn[r] > m[r]); }
    if (__any(change)) {
#pragma unroll
      for (int r = 0; r < 4; ++r) {
        float al = __expf(m[r] - mn[r]);
        lsum[r] *= al; m[r] = mn[r];
#pragma unroll
        for (int ct = 0; ct < 32; ++ct) o[ct][r] *= al;
      }
    }
    float ts[4] = {0.f, 0.f, 0.f, 0.f};
    unsigned short pb[4][4];
#pragma unroll
    for (int cc = 0; cc < 4; ++cc)
#pragma unroll
      for (int r = 0; r < 4; ++r) {
        float p = __expf(e[cc][r] - m[r]);
        ts[r] += p; pb[cc][r] = f2bf(p);
      }
#pragma unroll
    for (int off = 1; off < 16; off <<= 1)
#pragma unroll
      for (int r = 0; r < 4; ++r) ts[r] += __shfl_xor(ts[r], off);
#pragma unroll
    for (int r = 0; r < 4; ++r) lsum[r] += ts[r];

    unsigned short* Pw = sPf[wave];
#pragma unroll
    for (int cc = 0; cc < 4; ++cc)
#pragma unroll
      for (int r = 0; r < 4; ++r)
        Pw[(lg * 4 + r) * PPF + cc * 16 + ll] = pb[cc][r];
#pragma unroll
    for (int kc = 0; kc < 2; ++kc) {
      bf8 af = *(const bf8*)(Pw + ll * PPF + kc * 32 + lg * 8);
#pragma unroll
      for (int ct = 0; ct < 32; ++ct) {
        int d = ct * 16 + ll;
        bf8 vf = *(const bf8*)(sVt + d * 64 + (((kc * 4 + lg) ^ (d & 7) ^ ((d >> 3) & 7)) << 3));
        o[ct] = __builtin_amdgcn_mfma_f32_16x16x32_bf16(af, vf, o[ct], 0, 0, 0);
      }
    }
  }
  float inv[4];
#pragma unroll
  for (int r = 0; r < 4; ++r) inv[r] = 1.0f / lsum[r];
#pragma unroll
  for (int ct = 0; ct < 32; ++ct)
#pragma unroll
    for (int r = 0; r < 4; ++r) {
      size_t row = (size_t)b * Nn + q0 + lg * 4 + r;
      out[row * Dd + ct * 16 + ll] = o[ct][r] * inv[r];
    }
}

extern "C" void kernel_launch(void* const* d_in, const int* in_sizes, int n_in,
                              void* d_out, int out_size, void* d_ws, size_t ws_size,
                              hipStream_t stream) {
  (void)in_sizes; (void)n_in; (void)out_size;
  const float* X  = (const float*)d_in[0];
  const int* mask = (const int*)d_in[1];
  float* out = (float*)d_out;

  const size_t need = (size_t)Bb * NT * 65536;  // 32 MB of bf16 images
  if (ws_size >= need) {
    unsigned short* W = (unsigned short*)d_ws;
    build_images<<<dim3(NT, Bb), 256, 0, stream>>>(X, W);
    attn_ksplit<<<256, 512, 0, stream>>>(W, mask, out);
  } else {
    attn_fb<<<dim3(Nn / 64, Bb), 256, 0, stream>>>(X, mask, out);
  }
}